// Round 10
// baseline (569.420 us; speedup 1.0000x reference)
//
#include <hip/hip_runtime.h>

#define N_NODES 100000
#define N_PAD   100224   // padded row count for A-side buffers, 128-aligned
#define N_EDGES 800000
#define N_GRAPHS 64
#define D_IN 128
#define D_H 256

typedef __attribute__((ext_vector_type(8))) short bf16x8;
typedef __attribute__((ext_vector_type(8))) unsigned short u16x8;
typedef __attribute__((ext_vector_type(4))) float f32x4;

// ---------- bf16 helpers ----------
__device__ inline float bf2f(unsigned short u) {
    union { unsigned u32; float f; } x;
    x.u32 = ((unsigned)u) << 16;
    return x.f;
}
__device__ inline unsigned short f2bf(float f) {
    unsigned u = __float_as_uint(f);
    if ((u & 0x7fffffffu) > 0x7f800000u) return (unsigned short)0x7fc0;  // NaN
    unsigned r = ((u >> 16) & 1u) + 0x7fffu;
    return (unsigned short)((u + r) >> 16);
}

// ---------- order-preserving f32 <-> u32 for atomicMax ----------
__device__ inline unsigned enc_f32(float f) {
    unsigned u = __float_as_uint(f);
    return (u & 0x80000000u) ? ~u : (u | 0x80000000u);
}
__device__ inline float dec_f32(unsigned u) {
    unsigned v = (u & 0x80000000u) ? (u & 0x7FFFFFFFu) : ~u;
    return __uint_as_float(v);
}
#define ENC_NEG_INF 0x007FFFFFu

#define GLOAD_LDS16(g, l)                                                     \
    __builtin_amdgcn_global_load_lds(                                         \
        (const __attribute__((address_space(1))) unsigned int*)(g),           \
        (__attribute__((address_space(3))) unsigned int*)(l), 16, 0, 0)

// ================= CSR build =================
__global__ void k_init_counts(int* __restrict__ counts) {
    int i = blockIdx.x * blockDim.x + threadIdx.x;
    if (i < N_NODES) counts[i] = 0;
}

__global__ void k_count(const int* __restrict__ dst, int* __restrict__ counts) {
    int e = blockIdx.x * blockDim.x + threadIdx.x;
    if (e < N_EDGES) atomicAdd(&counts[dst[e]], 1);
}

__global__ void k_scan_block(const int* __restrict__ counts, int* __restrict__ excl,
                             int* __restrict__ bsums) {
    __shared__ int sh[1024];
    int tid = threadIdx.x;
    int i = blockIdx.x * 1024 + tid;
    int v = (i < N_NODES) ? counts[i] : 0;
    sh[tid] = v;
    __syncthreads();
    for (int off = 1; off < 1024; off <<= 1) {
        int t = (tid >= off) ? sh[tid - off] : 0;
        __syncthreads();
        sh[tid] += t;
        __syncthreads();
    }
    if (i < N_NODES) excl[i] = sh[tid] - v;
    if (tid == 1023) bsums[blockIdx.x] = sh[1023];
}

__global__ void k_scan_top(int* __restrict__ bsums, int nb) {
    __shared__ int sh[128];
    int tid = threadIdx.x;
    int v = (tid < nb) ? bsums[tid] : 0;
    sh[tid] = v;
    __syncthreads();
    for (int off = 1; off < 128; off <<= 1) {
        int t = (tid >= off) ? sh[tid - off] : 0;
        __syncthreads();
        sh[tid] += t;
        __syncthreads();
    }
    if (tid < nb) bsums[tid] = sh[tid] - v;
}

__global__ void k_scan_finish(const int* __restrict__ excl, const int* __restrict__ bsums,
                              const int* __restrict__ counts, int* __restrict__ indptr,
                              int* __restrict__ cursor, float* __restrict__ deg_inv,
                              unsigned* __restrict__ pooled) {
    int i = blockIdx.x * blockDim.x + threadIdx.x;
    if (i < N_GRAPHS * 256) pooled[i] = ENC_NEG_INF;  // fold pool_init here
    if (i < N_NODES) {
        int p = excl[i] + bsums[i >> 10];
        indptr[i] = p;
        cursor[i] = p;
        deg_inv[i] = 1.0f / fmaxf((float)counts[i], 1.0f);
        if (i == 0) indptr[N_NODES] = N_EDGES;
    }
}

__global__ void k_fill(const int* __restrict__ src, const int* __restrict__ dst,
                       int* __restrict__ cursor, int* __restrict__ eidx) {
    int e = blockIdx.x * blockDim.x + threadIdx.x;
    if (e < N_EDGES) {
        int pos = atomicAdd(&cursor[dst[e]], 1);
        eidx[pos] = src[e];
    }
}

// ================= conversions =================
__global__ void k_x2bf(const float* __restrict__ x, unsigned short* __restrict__ hx) {
    const int total = N_NODES * D_IN / 4;
    for (int i = blockIdx.x * blockDim.x + threadIdx.x; i < total;
         i += gridDim.x * blockDim.x) {
        float4 v = reinterpret_cast<const float4*>(x)[i];
        ushort4 o;
        o.x = f2bf(v.x); o.y = f2bf(v.y); o.z = f2bf(v.z); o.w = f2bf(v.w);
        reinterpret_cast<ushort4*>(hx)[i] = o;
    }
}

// All six W [K][256] f32 -> Wt [256][K] bf16 in one launch.
__global__ void k_wt_all(const float* __restrict__ W1l, const float* __restrict__ W1r,
                         const float* __restrict__ W2l, const float* __restrict__ W2r,
                         const float* __restrict__ W3l, const float* __restrict__ W3r,
                         unsigned short* __restrict__ T1l, unsigned short* __restrict__ T1r,
                         unsigned short* __restrict__ T2l, unsigned short* __restrict__ T2r,
                         unsigned short* __restrict__ T3l, unsigned short* __restrict__ T3r) {
    const int S1 = 128 * 256, S2 = 256 * 256;
    const int total = 2 * S1 + 4 * S2;
    for (int idx = blockIdx.x * blockDim.x + threadIdx.x; idx < total;
         idx += gridDim.x * blockDim.x) {
        const float* W; unsigned short* T; int i, K;
        if (idx < S1)           { W = W1l; T = T1l; i = idx;            K = 128; }
        else if (idx < 2 * S1)  { W = W1r; T = T1r; i = idx - S1;       K = 128; }
        else if (idx < 2*S1+S2) { W = W2l; T = T2l; i = idx - 2*S1;     K = 256; }
        else if (idx < 2*S1+2*S2) { W = W2r; T = T2r; i = idx-2*S1-S2;  K = 256; }
        else if (idx < 2*S1+3*S2) { W = W3l; T = T3l; i = idx-2*S1-2*S2; K = 256; }
        else                    { W = W3r; T = T3r; i = idx-2*S1-3*S2;  K = 256; }
        int k = i >> 8, n = i & 255;
        T[n * K + k] = f2bf(W[(size_t)k * 256 + n]);
    }
}

// ================= aggregation: mean over CSR neighbors =================
// 512B rows; 16 lanes x 32B per row; 4 edges in flight per wave.
template <bool IN_F32>
__global__ void k_agg(const void* __restrict__ hin, const int* __restrict__ indptr,
                      const int* __restrict__ eidx, const float* __restrict__ deg_inv,
                      unsigned short* __restrict__ mean) {
    constexpr int D = IN_F32 ? 128 : 256;      // elems per row (512 B both)
    constexpr int CA = IN_F32 ? 8 : 16;        // accum elems per lane (32 B)
    int wid = (blockIdx.x * blockDim.x + threadIdx.x) >> 6;
    int lane = threadIdx.x & 63;
    int nw = (gridDim.x * blockDim.x) >> 6;
    int g = lane >> 4;        // edge slot 0..3
    int l16 = lane & 15;      // 16 lanes cover the 512B row, 32B each
    for (int node = wid; node < N_NODES; node += nw) {
        int beg = indptr[node], end = indptr[node + 1];
        float acc[CA] = {};
        for (int e = beg + g; e < end; e += 4) {
            int s = eidx[e];
            if (IN_F32) {
                const float4* row = reinterpret_cast<const float4*>((const float*)hin + (size_t)s * D);
                float4 v0 = row[l16 * 2], v1 = row[l16 * 2 + 1];
                acc[0] += v0.x; acc[1] += v0.y; acc[2] += v0.z; acc[3] += v0.w;
                acc[4] += v1.x; acc[5] += v1.y; acc[6] += v1.z; acc[7] += v1.w;
            } else {
                const u16x8* row = reinterpret_cast<const u16x8*>((const unsigned short*)hin + (size_t)s * D);
                u16x8 v0 = row[l16 * 2], v1 = row[l16 * 2 + 1];
#pragma unroll
                for (int j = 0; j < 8; ++j) acc[j] += bf2f((unsigned short)v0[j]);
#pragma unroll
                for (int j = 0; j < 8; ++j) acc[8 + j] += bf2f((unsigned short)v1[j]);
            }
        }
#pragma unroll
        for (int i = 0; i < CA; ++i) {
            acc[i] += __shfl_xor(acc[i], 16);
            acc[i] += __shfl_xor(acc[i], 32);
        }
        if (g == 0) {
            float inv = deg_inv[node];
            unsigned short* orow = mean + (size_t)node * (IN_F32 ? 128 : 256);
            if (IN_F32) {
                u16x8 o;
#pragma unroll
                for (int j = 0; j < 8; ++j) o[j] = f2bf(acc[j] * inv);
                reinterpret_cast<u16x8*>(orow)[l16] = o;
            } else {
                u16x8 o0, o1;
#pragma unroll
                for (int j = 0; j < 8; ++j) o0[j] = f2bf(acc[j] * inv);
#pragma unroll
                for (int j = 0; j < 8; ++j) o1[j] = f2bf(acc[8 + j] * inv);
                reinterpret_cast<u16x8*>(orow)[l16 * 2] = o0;
                reinterpret_cast<u16x8*>(orow)[l16 * 2 + 1] = o1;
            }
        }
    }
}

// ================= MFMA SAGE transform =================
// out[0:N_NODES][0:256] = act( mean @ Wl + h @ Wr + b )
// r7's winning structure (128x256 tile, 8 waves 2x4, single-buffer LDS,
// gload_lds, vmcnt(0)+syncthreads) with BK=64: half the drain count,
// double compute per step. New swizzle for 128B rows (8 x 16B chunks):
//   LDS[r][p] = src[r][p ^ (r&7)]  (involution on both sides)
// -> 16-lane column reads spread over all 32 banks (2-way, free).
template <int K, bool TANH, bool POOL>
__global__ __launch_bounds__(512)
void k_xform(const unsigned short* __restrict__ A0, const unsigned short* __restrict__ A1,
             const unsigned short* __restrict__ Bt0, const unsigned short* __restrict__ Bt1,
             const float* __restrict__ bias,
             unsigned short* __restrict__ out,
             const int* __restrict__ batch, unsigned* __restrict__ pooled) {
    __shared__ unsigned short Al[128 * 64];   // 16 KB
    __shared__ unsigned short Bl[256 * 64];   // 32 KB

    const int tid = threadIdx.x;
    const int lane = tid & 63;
    const int wid = tid >> 6;        // 0..7
    const int wr = wid >> 2;         // wave row (0..1)
    const int wc = wid & 3;          // wave col (0..3)
    const int m0 = blockIdx.x * 128;

    // stage-side: one gload round covers 8 rows x 8 chunks (64 lanes x 16B).
    // lane l -> local row l>>3, LDS chunk l&7, source chunk (l&7)^(l>>3).
    const int srow8 = lane >> 3;                 // 0..7
    const int koffs = ((lane & 7) ^ srow8) * 8;  // swizzled source element offset

    f32x4 acc[4][4] = {};

#pragma unroll
    for (int slab = 0; slab < 2; ++slab) {
        const unsigned short* As = slab ? A1 : A0;
        const unsigned short* Bs = slab ? Bt1 : Bt0;
        for (int k0 = 0; k0 < K; k0 += 64) {
            __syncthreads();  // previous compute done before overwrite
            // A: 128 rows = 16 rounds of 8 rows; 2 rounds per wave
#pragma unroll
            for (int g = 0; g < 2; ++g) {
                int rb = (wid * 2 + g) * 8;
                GLOAD_LDS16(As + (size_t)(m0 + rb + srow8) * K + k0 + koffs,
                            &Al[rb * 64]);
            }
            // B: 256 rows = 32 rounds; 4 per wave
#pragma unroll
            for (int g = 0; g < 4; ++g) {
                int rb = (wid * 4 + g) * 8;
                GLOAD_LDS16(Bs + (size_t)(rb + srow8) * K + k0 + koffs,
                            &Bl[rb * 64]);
            }
            asm volatile("s_waitcnt vmcnt(0)" ::: "memory");
            __syncthreads();

#pragma unroll
            for (int ks = 0; ks < 2; ++ks) {
                bf16x8 af[4], bfr[4];
#pragma unroll
                for (int f = 0; f < 4; ++f) {
                    int ra = wr * 64 + f * 16 + (lane & 15);
                    int ca = (ks * 4 + (lane >> 4)) ^ (ra & 7);
                    af[f] = *reinterpret_cast<const bf16x8*>(&Al[ra * 64 + ca * 8]);
                    int rb2 = wc * 64 + f * 16 + (lane & 15);
                    int cb = (ks * 4 + (lane >> 4)) ^ (rb2 & 7);
                    bfr[f] = *reinterpret_cast<const bf16x8*>(&Bl[rb2 * 64 + cb * 8]);
                }
#pragma unroll
                for (int fi = 0; fi < 4; ++fi)
#pragma unroll
                    for (int fj = 0; fj < 4; ++fj)
                        acc[fi][fj] = __builtin_amdgcn_mfma_f32_16x16x32_bf16(
                            af[fi], bfr[fj], acc[fi][fj], 0, 0, 0);
            }
        }
    }

    // epilogue: D mapping per frag: row = (lane>>4)*4 + r, col = lane&15
    const int rbase = m0 + wr * 64 + (lane >> 4) * 4;
    const int cbase = wc * 64 + (lane & 15);
    if (POOL) {
#pragma unroll
        for (int fj = 0; fj < 4; ++fj) {
            int col = cbase + fj * 16;
            float bcol = bias[col];
            int curg = -1;
            float curmax = 0.f;
#pragma unroll
            for (int fi = 0; fi < 4; ++fi) {
#pragma unroll
                for (int r = 0; r < 4; ++r) {
                    int row = rbase + fi * 16 + r;
                    if (row >= N_NODES) continue;
                    float v = acc[fi][fj][r] + bcol;
                    if (TANH) v = tanhf(v);
                    int g = batch[row];
                    if (g != curg) {
                        if (curg >= 0) atomicMax(&pooled[curg * 256 + col], enc_f32(curmax));
                        curg = g;
                        curmax = v;
                    } else {
                        curmax = fmaxf(curmax, v);
                    }
                }
            }
            if (curg >= 0) atomicMax(&pooled[curg * 256 + col], enc_f32(curmax));
        }
    } else {
#pragma unroll
        for (int fi = 0; fi < 4; ++fi) {
#pragma unroll
            for (int fj = 0; fj < 4; ++fj) {
                int col = cbase + fj * 16;
                float bcol = bias[col];
#pragma unroll
                for (int r = 0; r < 4; ++r) {
                    int row = rbase + fi * 16 + r;
                    if (row >= N_NODES) continue;
                    float v = acc[fi][fj][r] + bcol;
                    if (TANH) v = tanhf(v);
                    out[(size_t)row * 256 + col] = f2bf(v);
                }
            }
        }
    }
}

// ================= head =================
__global__ void k_head(const unsigned* __restrict__ pooled,
                       const float* __restrict__ W1, const float* __restrict__ b1,
                       const float* __restrict__ W2, const float* __restrict__ b2,
                       float* __restrict__ out) {
    __shared__ float p[256];
    __shared__ float hm[64];
    int g = blockIdx.x;
    int t = threadIdx.x;  // 64 threads
    for (int k = t; k < 256; k += 64) {
        unsigned u = pooled[g * 256 + k];
        p[k] = (u == ENC_NEG_INF) ? 0.0f : dec_f32(u);
    }
    __syncthreads();
    float a = b1[t];
    for (int k = 0; k < 256; ++k) a += p[k] * W1[k * 64 + t];
    hm[t] = tanhf(a);
    __syncthreads();
    if (t < 3) {
        float o = b2[t];
        for (int m = 0; m < 64; ++m) o += hm[m] * W2[m * 3 + t];
        out[g * 3 + t] = o;
    }
}

extern "C" void kernel_launch(void* const* d_in, const int* in_sizes, int n_in,
                              void* d_out, int out_size, void* d_ws, size_t ws_size,
                              hipStream_t stream) {
    const float* x     = (const float*)d_in[0];
    const int*   ei    = (const int*)d_in[1];
    const int*   src   = ei;
    const int*   dst   = ei + N_EDGES;
    const int*   batch = (const int*)d_in[2];
    const float* W1l = (const float*)d_in[3];
    const float* b1l = (const float*)d_in[4];
    const float* W1r = (const float*)d_in[5];
    const float* W2l = (const float*)d_in[6];
    const float* b2l = (const float*)d_in[7];
    const float* W2r = (const float*)d_in[8];
    const float* W3l = (const float*)d_in[9];
    const float* b3l = (const float*)d_in[10];
    const float* W3r = (const float*)d_in[11];
    const float* Wlin1 = (const float*)d_in[12];
    const float* blin1 = (const float*)d_in[13];
    const float* Wlin2 = (const float*)d_in[14];
    const float* blin2 = (const float*)d_in[15];
    float* out = (float*)d_out;

    // ---- workspace layout (~159 MB) ----
    char* base = (char*)d_ws;
    size_t off = 0;
    auto alloc = [&](size_t bytes) { char* p = base + off; off += (bytes + 255) & ~(size_t)255; return (void*)p; };
    int*   counts  = (int*)alloc(N_NODES * 4);
    int*   indptr  = (int*)alloc((N_NODES + 1) * 4);
    int*   cursor  = (int*)alloc(N_NODES * 4);
    int*   excl    = (int*)alloc(N_NODES * 4);
    int*   bsums   = (int*)alloc(128 * 4);
    float* deg_inv = (float*)alloc(N_NODES * 4);
    unsigned* pooled = (unsigned*)alloc(N_GRAPHS * 256 * 4);
    int*   eidx    = (int*)alloc(N_EDGES * 4);
    unsigned short* Wt1l = (unsigned short*)alloc(256 * 128 * 2);
    unsigned short* Wt1r = (unsigned short*)alloc(256 * 128 * 2);
    unsigned short* Wt2l = (unsigned short*)alloc(256 * 256 * 2);
    unsigned short* Wt2r = (unsigned short*)alloc(256 * 256 * 2);
    unsigned short* Wt3l = (unsigned short*)alloc(256 * 256 * 2);
    unsigned short* Wt3r = (unsigned short*)alloc(256 * 256 * 2);
    unsigned short* M   = (unsigned short*)alloc((size_t)N_PAD * 256 * 2);
    unsigned short* hA  = (unsigned short*)alloc((size_t)N_PAD * 256 * 2);
    unsigned short* hxB = (unsigned short*)alloc((size_t)N_PAD * 256 * 2);  // hx (conv1), then hB
    unsigned short* hx = hxB;
    unsigned short* hB = hxB;

    const int NB_SCAN = (N_NODES + 1023) / 1024;

    // ---- CSR build ----
    k_init_counts<<<(N_NODES + 255) / 256, 256, 0, stream>>>(counts);
    k_count<<<(N_EDGES + 255) / 256, 256, 0, stream>>>(dst, counts);
    k_scan_block<<<NB_SCAN, 1024, 0, stream>>>(counts, excl, bsums);
    k_scan_top<<<1, 128, 0, stream>>>(bsums, NB_SCAN);
    k_scan_finish<<<(N_NODES + 255) / 256, 256, 0, stream>>>(excl, bsums, counts, indptr, cursor, deg_inv, pooled);
    k_fill<<<(N_EDGES + 255) / 256, 256, 0, stream>>>(src, dst, cursor, eidx);

    // ---- conversions ----
    k_x2bf<<<2048, 256, 0, stream>>>(x, hx);
    k_wt_all<<<1280, 256, 0, stream>>>(W1l, W1r, W2l, W2r, W3l, W3r,
                                       Wt1l, Wt1r, Wt2l, Wt2r, Wt3l, Wt3r);

    dim3 ggrid(782);  // 782*128 = 100096 rows; full 256 cols per block

    // ---- conv1: x -> hA ----
    k_agg<true><<<2048, 256, 0, stream>>>(x, indptr, eidx, deg_inv, M);
    k_xform<128, true, false><<<ggrid, 512, 0, stream>>>(M, hx, Wt1l, Wt1r, b1l, hA, nullptr, nullptr);

    // ---- conv2: hA -> hB (hx dead from here) ----
    k_agg<false><<<2048, 256, 0, stream>>>(hA, indptr, eidx, deg_inv, M);
    k_xform<256, true, false><<<ggrid, 512, 0, stream>>>(M, hA, Wt2l, Wt2r, b2l, hB, nullptr, nullptr);

    // ---- conv3: hB -> pooled (fused segment-max) ----
    k_agg<false><<<2048, 256, 0, stream>>>(hB, indptr, eidx, deg_inv, M);
    k_xform<256, false, true><<<ggrid, 512, 0, stream>>>(M, hB, Wt3l, Wt3r, b3l, nullptr, batch, pooled);

    // ---- head ----
    k_head<<<N_GRAPHS, 64, 0, stream>>>(pooled, Wlin1, blin1, Wlin2, blin2, out);
}

// Round 11
// 500.510 us; speedup vs baseline: 1.1377x; 1.1377x over previous
//
#include <hip/hip_runtime.h>

#define N_NODES 100000
#define N_PAD   100224   // padded row count for A-side buffers, 128-aligned
#define N_EDGES 800000
#define N_GRAPHS 64
#define D_IN 128
#define D_H 256

typedef __attribute__((ext_vector_type(8))) short bf16x8;
typedef __attribute__((ext_vector_type(8))) unsigned short u16x8;
typedef __attribute__((ext_vector_type(4))) float f32x4;

// ---------- bf16 helpers ----------
__device__ inline float bf2f(unsigned short u) {
    union { unsigned u32; float f; } x;
    x.u32 = ((unsigned)u) << 16;
    return x.f;
}
__device__ inline unsigned short f2bf(float f) {
    unsigned u = __float_as_uint(f);
    if ((u & 0x7fffffffu) > 0x7f800000u) return (unsigned short)0x7fc0;  // NaN
    unsigned r = ((u >> 16) & 1u) + 0x7fffu;
    return (unsigned short)((u + r) >> 16);
}

// ---------- order-preserving f32 <-> u32 for atomicMax ----------
__device__ inline unsigned enc_f32(float f) {
    unsigned u = __float_as_uint(f);
    return (u & 0x80000000u) ? ~u : (u | 0x80000000u);
}
__device__ inline float dec_f32(unsigned u) {
    unsigned v = (u & 0x80000000u) ? (u & 0x7FFFFFFFu) : ~u;
    return __uint_as_float(v);
}
#define ENC_NEG_INF 0x007FFFFFu

#define GLOAD_LDS16(g, l)                                                     \
    __builtin_amdgcn_global_load_lds(                                         \
        (const __attribute__((address_space(1))) unsigned int*)(g),           \
        (__attribute__((address_space(3))) unsigned int*)(l), 16, 0, 0)

// ================= CSR build =================
__global__ void k_init_counts(int* __restrict__ counts) {
    int i = blockIdx.x * blockDim.x + threadIdx.x;
    if (i < N_NODES) counts[i] = 0;
}

__global__ void k_count(const int* __restrict__ dst, int* __restrict__ counts) {
    int e = blockIdx.x * blockDim.x + threadIdx.x;
    if (e < N_EDGES) atomicAdd(&counts[dst[e]], 1);
}

__global__ void k_scan_block(const int* __restrict__ counts, int* __restrict__ excl,
                             int* __restrict__ bsums) {
    __shared__ int sh[1024];
    int tid = threadIdx.x;
    int i = blockIdx.x * 1024 + tid;
    int v = (i < N_NODES) ? counts[i] : 0;
    sh[tid] = v;
    __syncthreads();
    for (int off = 1; off < 1024; off <<= 1) {
        int t = (tid >= off) ? sh[tid - off] : 0;
        __syncthreads();
        sh[tid] += t;
        __syncthreads();
    }
    if (i < N_NODES) excl[i] = sh[tid] - v;
    if (tid == 1023) bsums[blockIdx.x] = sh[1023];
}

__global__ void k_scan_top(int* __restrict__ bsums, int nb) {
    __shared__ int sh[128];
    int tid = threadIdx.x;
    int v = (tid < nb) ? bsums[tid] : 0;
    sh[tid] = v;
    __syncthreads();
    for (int off = 1; off < 128; off <<= 1) {
        int t = (tid >= off) ? sh[tid - off] : 0;
        __syncthreads();
        sh[tid] += t;
        __syncthreads();
    }
    if (tid < nb) bsums[tid] = sh[tid] - v;
}

__global__ void k_scan_finish(const int* __restrict__ excl, const int* __restrict__ bsums,
                              const int* __restrict__ counts, int* __restrict__ indptr,
                              int* __restrict__ cursor, float* __restrict__ deg_inv,
                              unsigned* __restrict__ pooled) {
    int i = blockIdx.x * blockDim.x + threadIdx.x;
    if (i < N_GRAPHS * 256) pooled[i] = ENC_NEG_INF;  // fold pool_init here
    if (i < N_NODES) {
        int p = excl[i] + bsums[i >> 10];
        indptr[i] = p;
        cursor[i] = p;
        deg_inv[i] = 1.0f / fmaxf((float)counts[i], 1.0f);
        if (i == 0) indptr[N_NODES] = N_EDGES;
    }
}

__global__ void k_fill(const int* __restrict__ src, const int* __restrict__ dst,
                       int* __restrict__ cursor, int* __restrict__ eidx) {
    int e = blockIdx.x * blockDim.x + threadIdx.x;
    if (e < N_EDGES) {
        int pos = atomicAdd(&cursor[dst[e]], 1);
        eidx[pos] = src[e];
    }
}

// ================= conversions =================
__global__ void k_x2bf(const float* __restrict__ x, unsigned short* __restrict__ hx) {
    const int total = N_NODES * D_IN / 4;
    for (int i = blockIdx.x * blockDim.x + threadIdx.x; i < total;
         i += gridDim.x * blockDim.x) {
        float4 v = reinterpret_cast<const float4*>(x)[i];
        ushort4 o;
        o.x = f2bf(v.x); o.y = f2bf(v.y); o.z = f2bf(v.z); o.w = f2bf(v.w);
        reinterpret_cast<ushort4*>(hx)[i] = o;
    }
}

// All six W [K][256] f32 -> Wt [256][K] bf16 in one launch.
__global__ void k_wt_all(const float* __restrict__ W1l, const float* __restrict__ W1r,
                         const float* __restrict__ W2l, const float* __restrict__ W2r,
                         const float* __restrict__ W3l, const float* __restrict__ W3r,
                         unsigned short* __restrict__ T1l, unsigned short* __restrict__ T1r,
                         unsigned short* __restrict__ T2l, unsigned short* __restrict__ T2r,
                         unsigned short* __restrict__ T3l, unsigned short* __restrict__ T3r) {
    const int S1 = 128 * 256, S2 = 256 * 256;
    const int total = 2 * S1 + 4 * S2;
    for (int idx = blockIdx.x * blockDim.x + threadIdx.x; idx < total;
         idx += gridDim.x * blockDim.x) {
        const float* W; unsigned short* T; int i, K;
        if (idx < S1)           { W = W1l; T = T1l; i = idx;            K = 128; }
        else if (idx < 2 * S1)  { W = W1r; T = T1r; i = idx - S1;       K = 128; }
        else if (idx < 2*S1+S2) { W = W2l; T = T2l; i = idx - 2*S1;     K = 256; }
        else if (idx < 2*S1+2*S2) { W = W2r; T = T2r; i = idx-2*S1-S2;  K = 256; }
        else if (idx < 2*S1+3*S2) { W = W3l; T = T3l; i = idx-2*S1-2*S2; K = 256; }
        else                    { W = W3r; T = T3r; i = idx-2*S1-3*S2;  K = 256; }
        int k = i >> 8, n = i & 255;
        T[n * K + k] = f2bf(W[(size_t)k * 256 + n]);
    }
}

// ================= aggregation: mean over CSR neighbors =================
// LDS-staged indices: each block owns 64 consecutive nodes; indptr (65 ints)
// and all edge indices (<=1152, avg 512) are loaded coalesced into LDS first,
// removing the per-node dependent chain indptr->eidx->gather. Overflow tail
// (astronomically rare) falls back to global eidx reads — same values.
// D=128: bf16 rows of 256B, 16 lanes x 16B; D=256: 512B rows, 16 lanes x 32B.
// 4 edges in flight per wave (lane groups), shfl reduction across groups.
template <int D>
__global__ __launch_bounds__(256)
void k_agg(const unsigned short* __restrict__ hin, const int* __restrict__ indptr,
           const int* __restrict__ eidx, const float* __restrict__ deg_inv,
           unsigned short* __restrict__ mean) {
    constexpr int NB = 64;
    constexpr int ECAP = 1152;
    constexpr int CA = (D == 128) ? 8 : 16;   // f32 accum elems per lane
    __shared__ int sptr[NB + 1];
    __shared__ int sedge[ECAP];

    const int n0 = blockIdx.x * NB;
    const int tid = threadIdx.x;

    if (tid <= NB) {
        int n = n0 + tid;
        sptr[tid] = indptr[n < N_NODES ? n : N_NODES];
    }
    __syncthreads();
    const int ebeg = sptr[0];
    const int ecnt = sptr[NB] - ebeg;
    const int estaged = ecnt < ECAP ? ecnt : ECAP;
    for (int i = tid; i < estaged; i += 256) sedge[i] = eidx[ebeg + i];
    __syncthreads();

    const int wv = tid >> 6;     // 0..3: wave handles nodes n0+wv*16 .. +15
    const int lane = tid & 63;
    const int g = lane >> 4;     // edge slot 0..3
    const int l16 = lane & 15;   // 16 lanes cover one row

    for (int i = 0; i < 16; ++i) {
        int ln = wv * 16 + i;
        int node = n0 + ln;
        if (node >= N_NODES) break;
        int b = sptr[ln] - ebeg, e = sptr[ln + 1] - ebeg;
        float acc[CA] = {};
        for (int j = b + g; j < e; j += 4) {
            int s = (j < ECAP) ? sedge[j] : eidx[ebeg + j];
            const u16x8* row = reinterpret_cast<const u16x8*>(hin + (size_t)s * D);
            if (D == 128) {
                u16x8 v = row[l16];
#pragma unroll
                for (int c = 0; c < 8; ++c) acc[c] += bf2f((unsigned short)v[c]);
            } else {
                u16x8 v0 = row[l16 * 2], v1 = row[l16 * 2 + 1];
#pragma unroll
                for (int c = 0; c < 8; ++c) acc[c] += bf2f((unsigned short)v0[c]);
#pragma unroll
                for (int c = 0; c < 8; ++c) acc[8 + c] += bf2f((unsigned short)v1[c]);
            }
        }
#pragma unroll
        for (int c = 0; c < CA; ++c) {
            acc[c] += __shfl_xor(acc[c], 16);
            acc[c] += __shfl_xor(acc[c], 32);
        }
        if (g == 0) {
            float inv = deg_inv[node];
            unsigned short* orow = mean + (size_t)node * D;
            if (D == 128) {
                u16x8 o;
#pragma unroll
                for (int c = 0; c < 8; ++c) o[c] = f2bf(acc[c] * inv);
                reinterpret_cast<u16x8*>(orow)[l16] = o;
            } else {
                u16x8 o0, o1;
#pragma unroll
                for (int c = 0; c < 8; ++c) o0[c] = f2bf(acc[c] * inv);
#pragma unroll
                for (int c = 0; c < 8; ++c) o1[c] = f2bf(acc[8 + c] * inv);
                reinterpret_cast<u16x8*>(orow)[l16 * 2] = o0;
                reinterpret_cast<u16x8*>(orow)[l16 * 2 + 1] = o1;
            }
        }
    }
}

// ================= MFMA SAGE transform =================
// r7-verified 75us version, unchanged: 128x256 tile, BK=32, 8 waves (2x4),
// single-buffer LDS, gload_lds, vmcnt(0)+syncthreads, XOR chunk swizzle
// (LDS[r][p] = src[r][p^((r>>1)&3)], involution both sides, conflicts ~0).
template <int K, bool TANH, bool POOL>
__global__ __launch_bounds__(512)
void k_xform(const unsigned short* __restrict__ A0, const unsigned short* __restrict__ A1,
             const unsigned short* __restrict__ Bt0, const unsigned short* __restrict__ Bt1,
             const float* __restrict__ bias,
             unsigned short* __restrict__ out,
             const int* __restrict__ batch, unsigned* __restrict__ pooled) {
    __shared__ unsigned short Al[128 * 32];
    __shared__ unsigned short Bl[256 * 32];

    const int tid = threadIdx.x;
    const int lane = tid & 63;
    const int wid = tid >> 6;        // 0..7
    const int wr = wid >> 2;         // wave row (0..1)
    const int wc = wid & 3;          // wave col (0..3)
    const int m0 = blockIdx.x * 128;

    const int srow = lane >> 2;                         // 0..15 within 16-row group
    const int koffs = ((lane & 3) ^ ((lane >> 3) & 3)) * 8;

    f32x4 acc[4][4] = {};

#pragma unroll
    for (int slab = 0; slab < 2; ++slab) {
        const unsigned short* As = slab ? A1 : A0;
        const unsigned short* Bs = slab ? Bt1 : Bt0;
        for (int k0 = 0; k0 < K; k0 += 32) {
            __syncthreads();  // previous compute done before overwrite
            GLOAD_LDS16(As + (size_t)(m0 + wid * 16 + srow) * K + k0 + koffs,
                        &Al[wid * 512]);
#pragma unroll
            for (int cc = 0; cc < 2; ++cc) {
                int c = wid * 2 + cc;
                GLOAD_LDS16(Bs + (size_t)(c * 16 + srow) * K + k0 + koffs,
                            &Bl[c * 512]);
            }
            asm volatile("s_waitcnt vmcnt(0)" ::: "memory");
            __syncthreads();

            bf16x8 af[4], bfr[4];
#pragma unroll
            for (int f = 0; f < 4; ++f) {
                int ra = wr * 64 + f * 16 + (lane & 15);
                int pa = ((lane >> 4) ^ ((ra >> 1) & 3)) * 8;
                af[f] = *reinterpret_cast<const bf16x8*>(&Al[ra * 32 + pa]);
                int rb = wc * 64 + f * 16 + (lane & 15);
                int pb = ((lane >> 4) ^ ((rb >> 1) & 3)) * 8;
                bfr[f] = *reinterpret_cast<const bf16x8*>(&Bl[rb * 32 + pb]);
            }
#pragma unroll
            for (int fi = 0; fi < 4; ++fi)
#pragma unroll
                for (int fj = 0; fj < 4; ++fj)
                    acc[fi][fj] = __builtin_amdgcn_mfma_f32_16x16x32_bf16(
                        af[fi], bfr[fj], acc[fi][fj], 0, 0, 0);
        }
    }

    // epilogue: D mapping per frag: row = (lane>>4)*4 + r, col = lane&15
    const int rbase = m0 + wr * 64 + (lane >> 4) * 4;
    const int cbase = wc * 64 + (lane & 15);
    if (POOL) {
#pragma unroll
        for (int fj = 0; fj < 4; ++fj) {
            int col = cbase + fj * 16;
            float bcol = bias[col];
            int curg = -1;
            float curmax = 0.f;
#pragma unroll
            for (int fi = 0; fi < 4; ++fi) {
#pragma unroll
                for (int r = 0; r < 4; ++r) {
                    int row = rbase + fi * 16 + r;
                    if (row >= N_NODES) continue;
                    float v = acc[fi][fj][r] + bcol;
                    if (TANH) v = tanhf(v);
                    int g = batch[row];
                    if (g != curg) {
                        if (curg >= 0) atomicMax(&pooled[curg * 256 + col], enc_f32(curmax));
                        curg = g;
                        curmax = v;
                    } else {
                        curmax = fmaxf(curmax, v);
                    }
                }
            }
            if (curg >= 0) atomicMax(&pooled[curg * 256 + col], enc_f32(curmax));
        }
    } else {
#pragma unroll
        for (int fi = 0; fi < 4; ++fi) {
#pragma unroll
            for (int fj = 0; fj < 4; ++fj) {
                int col = cbase + fj * 16;
                float bcol = bias[col];
#pragma unroll
                for (int r = 0; r < 4; ++r) {
                    int row = rbase + fi * 16 + r;
                    if (row >= N_NODES) continue;
                    float v = acc[fi][fj][r] + bcol;
                    if (TANH) v = tanhf(v);
                    out[(size_t)row * 256 + col] = f2bf(v);
                }
            }
        }
    }
}

// ================= head =================
__global__ void k_head(const unsigned* __restrict__ pooled,
                       const float* __restrict__ W1, const float* __restrict__ b1,
                       const float* __restrict__ W2, const float* __restrict__ b2,
                       float* __restrict__ out) {
    __shared__ float p[256];
    __shared__ float hm[64];
    int g = blockIdx.x;
    int t = threadIdx.x;  // 64 threads
    for (int k = t; k < 256; k += 64) {
        unsigned u = pooled[g * 256 + k];
        p[k] = (u == ENC_NEG_INF) ? 0.0f : dec_f32(u);
    }
    __syncthreads();
    float a = b1[t];
    for (int k = 0; k < 256; ++k) a += p[k] * W1[k * 64 + t];
    hm[t] = tanhf(a);
    __syncthreads();
    if (t < 3) {
        float o = b2[t];
        for (int m = 0; m < 64; ++m) o += hm[m] * W2[m * 3 + t];
        out[g * 3 + t] = o;
    }
}

extern "C" void kernel_launch(void* const* d_in, const int* in_sizes, int n_in,
                              void* d_out, int out_size, void* d_ws, size_t ws_size,
                              hipStream_t stream) {
    const float* x     = (const float*)d_in[0];
    const int*   ei    = (const int*)d_in[1];
    const int*   src   = ei;
    const int*   dst   = ei + N_EDGES;
    const int*   batch = (const int*)d_in[2];
    const float* W1l = (const float*)d_in[3];
    const float* b1l = (const float*)d_in[4];
    const float* W1r = (const float*)d_in[5];
    const float* W2l = (const float*)d_in[6];
    const float* b2l = (const float*)d_in[7];
    const float* W2r = (const float*)d_in[8];
    const float* W3l = (const float*)d_in[9];
    const float* b3l = (const float*)d_in[10];
    const float* W3r = (const float*)d_in[11];
    const float* Wlin1 = (const float*)d_in[12];
    const float* blin1 = (const float*)d_in[13];
    const float* Wlin2 = (const float*)d_in[14];
    const float* blin2 = (const float*)d_in[15];
    float* out = (float*)d_out;

    // ---- workspace layout (~159 MB) ----
    char* base = (char*)d_ws;
    size_t off = 0;
    auto alloc = [&](size_t bytes) { char* p = base + off; off += (bytes + 255) & ~(size_t)255; return (void*)p; };
    int*   counts  = (int*)alloc(N_NODES * 4);
    int*   indptr  = (int*)alloc((N_NODES + 1) * 4);
    int*   cursor  = (int*)alloc(N_NODES * 4);
    int*   excl    = (int*)alloc(N_NODES * 4);
    int*   bsums   = (int*)alloc(128 * 4);
    float* deg_inv = (float*)alloc(N_NODES * 4);
    unsigned* pooled = (unsigned*)alloc(N_GRAPHS * 256 * 4);
    int*   eidx    = (int*)alloc(N_EDGES * 4);
    unsigned short* Wt1l = (unsigned short*)alloc(256 * 128 * 2);
    unsigned short* Wt1r = (unsigned short*)alloc(256 * 128 * 2);
    unsigned short* Wt2l = (unsigned short*)alloc(256 * 256 * 2);
    unsigned short* Wt2r = (unsigned short*)alloc(256 * 256 * 2);
    unsigned short* Wt3l = (unsigned short*)alloc(256 * 256 * 2);
    unsigned short* Wt3r = (unsigned short*)alloc(256 * 256 * 2);
    unsigned short* M   = (unsigned short*)alloc((size_t)N_PAD * 256 * 2);
    unsigned short* hA  = (unsigned short*)alloc((size_t)N_PAD * 256 * 2);
    unsigned short* hxB = (unsigned short*)alloc((size_t)N_PAD * 256 * 2);  // hx (conv1), then hB
    unsigned short* hx = hxB;
    unsigned short* hB = hxB;

    const int NB_SCAN = (N_NODES + 1023) / 1024;
    const int NB_AGG = (N_NODES + 63) / 64;  // 1563

    // ---- CSR build ----
    k_init_counts<<<(N_NODES + 255) / 256, 256, 0, stream>>>(counts);
    k_count<<<(N_EDGES + 255) / 256, 256, 0, stream>>>(dst, counts);
    k_scan_block<<<NB_SCAN, 1024, 0, stream>>>(counts, excl, bsums);
    k_scan_top<<<1, 128, 0, stream>>>(bsums, NB_SCAN);
    k_scan_finish<<<(N_NODES + 255) / 256, 256, 0, stream>>>(excl, bsums, counts, indptr, cursor, deg_inv, pooled);
    k_fill<<<(N_EDGES + 255) / 256, 256, 0, stream>>>(src, dst, cursor, eidx);

    // ---- conversions ----
    k_x2bf<<<2048, 256, 0, stream>>>(x, hx);
    k_wt_all<<<1280, 256, 0, stream>>>(W1l, W1r, W2l, W2r, W3l, W3r,
                                       Wt1l, Wt1r, Wt2l, Wt2r, Wt3l, Wt3r);

    dim3 ggrid(782);  // 782*128 = 100096 rows; full 256 cols per block

    // ---- conv1: x -> hA (gather + xform both on bf16 hx) ----
    k_agg<128><<<NB_AGG, 256, 0, stream>>>(hx, indptr, eidx, deg_inv, M);
    k_xform<128, true, false><<<ggrid, 512, 0, stream>>>(M, hx, Wt1l, Wt1r, b1l, hA, nullptr, nullptr);

    // ---- conv2: hA -> hB (hx dead from here) ----
    k_agg<256><<<NB_AGG, 256, 0, stream>>>(hA, indptr, eidx, deg_inv, M);
    k_xform<256, true, false><<<ggrid, 512, 0, stream>>>(M, hA, Wt2l, Wt2r, b2l, hB, nullptr, nullptr);

    // ---- conv3: hB -> pooled (fused segment-max) ----
    k_agg<256><<<NB_AGG, 256, 0, stream>>>(hB, indptr, eidx, deg_inv, M);
    k_xform<256, false, true><<<ggrid, 512, 0, stream>>>(M, hB, Wt3l, Wt3r, b3l, nullptr, batch, pooled);

    // ---- head ----
    k_head<<<N_GRAPHS, 64, 0, stream>>>(pooled, Wlin1, blin1, Wlin2, blin2, out);
}

// Round 12
// 455.121 us; speedup vs baseline: 1.2511x; 1.0997x over previous
//
#include <hip/hip_runtime.h>

#define N_NODES 100000
#define N_PAD   100224   // padded row count for A-side buffers, 128-aligned
#define N_EDGES 800000
#define N_GRAPHS 64
#define D_IN 128
#define D_H 256

typedef __attribute__((ext_vector_type(8))) short bf16x8;
typedef __attribute__((ext_vector_type(8))) unsigned short u16x8;
typedef __attribute__((ext_vector_type(4))) float f32x4;

// ---------- bf16 helpers ----------
__device__ inline float bf2f(unsigned short u) {
    union { unsigned u32; float f; } x;
    x.u32 = ((unsigned)u) << 16;
    return x.f;
}
__device__ inline unsigned short f2bf(float f) {
    unsigned u = __float_as_uint(f);
    if ((u & 0x7fffffffu) > 0x7f800000u) return (unsigned short)0x7fc0;  // NaN
    unsigned r = ((u >> 16) & 1u) + 0x7fffu;
    return (unsigned short)((u + r) >> 16);
}

// fast tanh: 1 - 2/(1+2^(2x*log2e)); v_exp_f32 + v_rcp_f32, ~5 VALU ops.
// |err| ~1e-6; saturates correctly to +-1; NaN propagates.
__device__ inline float fast_tanh(float x) {
    float e = __builtin_exp2f(x * 2.8853900817779268f);
    return 1.0f - 2.0f * __builtin_amdgcn_rcpf(1.0f + e);
}

// ---------- order-preserving f32 <-> u32 for atomicMax ----------
__device__ inline unsigned enc_f32(float f) {
    unsigned u = __float_as_uint(f);
    return (u & 0x80000000u) ? ~u : (u | 0x80000000u);
}
__device__ inline float dec_f32(unsigned u) {
    unsigned v = (u & 0x80000000u) ? (u & 0x7FFFFFFFu) : ~u;
    return __uint_as_float(v);
}
#define ENC_NEG_INF 0x007FFFFFu

#define GLOAD_LDS16(g, l)                                                     \
    __builtin_amdgcn_global_load_lds(                                         \
        (const __attribute__((address_space(1))) unsigned int*)(g),           \
        (__attribute__((address_space(3))) unsigned int*)(l), 16, 0, 0)

// ================= CSR build =================
__global__ void k_init_counts(int* __restrict__ counts) {
    int i = blockIdx.x * blockDim.x + threadIdx.x;
    if (i < N_NODES) counts[i] = 0;
}

__global__ void k_count(const int* __restrict__ dst, int* __restrict__ counts) {
    int e = blockIdx.x * blockDim.x + threadIdx.x;
    if (e < N_EDGES) atomicAdd(&counts[dst[e]], 1);
}

__global__ void k_scan_block(const int* __restrict__ counts, int* __restrict__ excl,
                             int* __restrict__ bsums) {
    __shared__ int sh[1024];
    int tid = threadIdx.x;
    int i = blockIdx.x * 1024 + tid;
    int v = (i < N_NODES) ? counts[i] : 0;
    sh[tid] = v;
    __syncthreads();
    for (int off = 1; off < 1024; off <<= 1) {
        int t = (tid >= off) ? sh[tid - off] : 0;
        __syncthreads();
        sh[tid] += t;
        __syncthreads();
    }
    if (i < N_NODES) excl[i] = sh[tid] - v;
    if (tid == 1023) bsums[blockIdx.x] = sh[1023];
}

__global__ void k_scan_top(int* __restrict__ bsums, int nb) {
    __shared__ int sh[128];
    int tid = threadIdx.x;
    int v = (tid < nb) ? bsums[tid] : 0;
    sh[tid] = v;
    __syncthreads();
    for (int off = 1; off < 128; off <<= 1) {
        int t = (tid >= off) ? sh[tid - off] : 0;
        __syncthreads();
        sh[tid] += t;
        __syncthreads();
    }
    if (tid < nb) bsums[tid] = sh[tid] - v;
}

__global__ void k_scan_finish(const int* __restrict__ excl, const int* __restrict__ bsums,
                              const int* __restrict__ counts, int* __restrict__ indptr,
                              int* __restrict__ cursor, float* __restrict__ deg_inv,
                              unsigned* __restrict__ pooled) {
    int i = blockIdx.x * blockDim.x + threadIdx.x;
    if (i < N_GRAPHS * 256) pooled[i] = ENC_NEG_INF;  // fold pool_init here
    if (i < N_NODES) {
        int p = excl[i] + bsums[i >> 10];
        indptr[i] = p;
        cursor[i] = p;
        deg_inv[i] = 1.0f / fmaxf((float)counts[i], 1.0f);
        if (i == 0) indptr[N_NODES] = N_EDGES;
    }
}

__global__ void k_fill(const int* __restrict__ src, const int* __restrict__ dst,
                       int* __restrict__ cursor, int* __restrict__ eidx) {
    int e = blockIdx.x * blockDim.x + threadIdx.x;
    if (e < N_EDGES) {
        int pos = atomicAdd(&cursor[dst[e]], 1);
        eidx[pos] = src[e];
    }
}

// ================= conversions =================
__global__ void k_x2bf(const float* __restrict__ x, unsigned short* __restrict__ hx) {
    const int total = N_NODES * D_IN / 4;
    for (int i = blockIdx.x * blockDim.x + threadIdx.x; i < total;
         i += gridDim.x * blockDim.x) {
        float4 v = reinterpret_cast<const float4*>(x)[i];
        ushort4 o;
        o.x = f2bf(v.x); o.y = f2bf(v.y); o.z = f2bf(v.z); o.w = f2bf(v.w);
        reinterpret_cast<ushort4*>(hx)[i] = o;
    }
}

// All six W [K][256] f32 -> Wt [256][K] bf16 in one launch.
__global__ void k_wt_all(const float* __restrict__ W1l, const float* __restrict__ W1r,
                         const float* __restrict__ W2l, const float* __restrict__ W2r,
                         const float* __restrict__ W3l, const float* __restrict__ W3r,
                         unsigned short* __restrict__ T1l, unsigned short* __restrict__ T1r,
                         unsigned short* __restrict__ T2l, unsigned short* __restrict__ T2r,
                         unsigned short* __restrict__ T3l, unsigned short* __restrict__ T3r) {
    const int S1 = 128 * 256, S2 = 256 * 256;
    const int total = 2 * S1 + 4 * S2;
    for (int idx = blockIdx.x * blockDim.x + threadIdx.x; idx < total;
         idx += gridDim.x * blockDim.x) {
        const float* W; unsigned short* T; int i, K;
        if (idx < S1)           { W = W1l; T = T1l; i = idx;            K = 128; }
        else if (idx < 2 * S1)  { W = W1r; T = T1r; i = idx - S1;       K = 128; }
        else if (idx < 2*S1+S2) { W = W2l; T = T2l; i = idx - 2*S1;     K = 256; }
        else if (idx < 2*S1+2*S2) { W = W2r; T = T2r; i = idx-2*S1-S2;  K = 256; }
        else if (idx < 2*S1+3*S2) { W = W3l; T = T3l; i = idx-2*S1-2*S2; K = 256; }
        else                    { W = W3r; T = T3r; i = idx-2*S1-3*S2;  K = 256; }
        int k = i >> 8, n = i & 255;
        T[n * K + k] = f2bf(W[(size_t)k * 256 + n]);
    }
}

// ================= aggregation: mean over CSR neighbors =================
// LDS-staged indices (r11-verified): block owns 64 nodes; indptr + edges in LDS.
template <int D>
__global__ __launch_bounds__(256)
void k_agg(const unsigned short* __restrict__ hin, const int* __restrict__ indptr,
           const int* __restrict__ eidx, const float* __restrict__ deg_inv,
           unsigned short* __restrict__ mean) {
    constexpr int NB = 64;
    constexpr int ECAP = 1152;
    constexpr int CA = (D == 128) ? 8 : 16;   // f32 accum elems per lane
    __shared__ int sptr[NB + 1];
    __shared__ int sedge[ECAP];

    const int n0 = blockIdx.x * NB;
    const int tid = threadIdx.x;

    if (tid <= NB) {
        int n = n0 + tid;
        sptr[tid] = indptr[n < N_NODES ? n : N_NODES];
    }
    __syncthreads();
    const int ebeg = sptr[0];
    const int ecnt = sptr[NB] - ebeg;
    const int estaged = ecnt < ECAP ? ecnt : ECAP;
    for (int i = tid; i < estaged; i += 256) sedge[i] = eidx[ebeg + i];
    __syncthreads();

    const int wv = tid >> 6;     // 0..3: wave handles nodes n0+wv*16 .. +15
    const int lane = tid & 63;
    const int g = lane >> 4;     // edge slot 0..3
    const int l16 = lane & 15;   // 16 lanes cover one row

    for (int i = 0; i < 16; ++i) {
        int ln = wv * 16 + i;
        int node = n0 + ln;
        if (node >= N_NODES) break;
        int b = sptr[ln] - ebeg, e = sptr[ln + 1] - ebeg;
        float acc[CA] = {};
        for (int j = b + g; j < e; j += 4) {
            int s = (j < ECAP) ? sedge[j] : eidx[ebeg + j];
            const u16x8* row = reinterpret_cast<const u16x8*>(hin + (size_t)s * D);
            if (D == 128) {
                u16x8 v = row[l16];
#pragma unroll
                for (int c = 0; c < 8; ++c) acc[c] += bf2f((unsigned short)v[c]);
            } else {
                u16x8 v0 = row[l16 * 2], v1 = row[l16 * 2 + 1];
#pragma unroll
                for (int c = 0; c < 8; ++c) acc[c] += bf2f((unsigned short)v0[c]);
#pragma unroll
                for (int c = 0; c < 8; ++c) acc[8 + c] += bf2f((unsigned short)v1[c]);
            }
        }
#pragma unroll
        for (int c = 0; c < CA; ++c) {
            acc[c] += __shfl_xor(acc[c], 16);
            acc[c] += __shfl_xor(acc[c], 32);
        }
        if (g == 0) {
            float inv = deg_inv[node];
            unsigned short* orow = mean + (size_t)node * D;
            if (D == 128) {
                u16x8 o;
#pragma unroll
                for (int c = 0; c < 8; ++c) o[c] = f2bf(acc[c] * inv);
                reinterpret_cast<u16x8*>(orow)[l16] = o;
            } else {
                u16x8 o0, o1;
#pragma unroll
                for (int c = 0; c < 8; ++c) o0[c] = f2bf(acc[c] * inv);
#pragma unroll
                for (int c = 0; c < 8; ++c) o1[c] = f2bf(acc[8 + c] * inv);
                reinterpret_cast<u16x8*>(orow)[l16 * 2] = o0;
                reinterpret_cast<u16x8*>(orow)[l16 * 2 + 1] = o1;
            }
        }
    }
}

// ================= MFMA SAGE transform =================
// r7-verified GEMM core (128x256, BK=32, 8 waves, single-buffer LDS, gload_lds,
// vmcnt(0)+syncthreads, XOR chunk swizzle). Epilogue reworked this round:
//  - fast_tanh (5 VALU) instead of libm tanhf (~20+)
//  - POOL: block-uniform-graph fast path -> LDS max-reduce (reusing GEMM LDS)
//    + 256 global atomics/block instead of ~16K.
template <int K, bool TANH, bool POOL>
__global__ __launch_bounds__(512)
void k_xform(const unsigned short* __restrict__ A0, const unsigned short* __restrict__ A1,
             const unsigned short* __restrict__ Bt0, const unsigned short* __restrict__ Bt1,
             const float* __restrict__ bias,
             unsigned short* __restrict__ out,
             const int* __restrict__ batch, unsigned* __restrict__ pooled) {
    __shared__ unsigned short Al[128 * 32];
    __shared__ unsigned short Bl[256 * 32];

    const int tid = threadIdx.x;
    const int lane = tid & 63;
    const int wid = tid >> 6;        // 0..7
    const int wr = wid >> 2;         // wave row (0..1)
    const int wc = wid & 3;          // wave col (0..3)
    const int m0 = blockIdx.x * 128;

    const int srow = lane >> 2;                         // 0..15 within 16-row group
    const int koffs = ((lane & 3) ^ ((lane >> 3) & 3)) * 8;

    f32x4 acc[4][4] = {};

#pragma unroll
    for (int slab = 0; slab < 2; ++slab) {
        const unsigned short* As = slab ? A1 : A0;
        const unsigned short* Bs = slab ? Bt1 : Bt0;
        for (int k0 = 0; k0 < K; k0 += 32) {
            __syncthreads();  // previous compute done before overwrite
            GLOAD_LDS16(As + (size_t)(m0 + wid * 16 + srow) * K + k0 + koffs,
                        &Al[wid * 512]);
#pragma unroll
            for (int cc = 0; cc < 2; ++cc) {
                int c = wid * 2 + cc;
                GLOAD_LDS16(Bs + (size_t)(c * 16 + srow) * K + k0 + koffs,
                            &Bl[c * 512]);
            }
            asm volatile("s_waitcnt vmcnt(0)" ::: "memory");
            __syncthreads();

            bf16x8 af[4], bfr[4];
#pragma unroll
            for (int f = 0; f < 4; ++f) {
                int ra = wr * 64 + f * 16 + (lane & 15);
                int pa = ((lane >> 4) ^ ((ra >> 1) & 3)) * 8;
                af[f] = *reinterpret_cast<const bf16x8*>(&Al[ra * 32 + pa]);
                int rb = wc * 64 + f * 16 + (lane & 15);
                int pb = ((lane >> 4) ^ ((rb >> 1) & 3)) * 8;
                bfr[f] = *reinterpret_cast<const bf16x8*>(&Bl[rb * 32 + pb]);
            }
#pragma unroll
            for (int fi = 0; fi < 4; ++fi)
#pragma unroll
                for (int fj = 0; fj < 4; ++fj)
                    acc[fi][fj] = __builtin_amdgcn_mfma_f32_16x16x32_bf16(
                        af[fi], bfr[fj], acc[fi][fj], 0, 0, 0);
        }
    }

    // epilogue: D mapping per frag: row = (lane>>4)*4 + r, col = lane&15
    const int rbase = m0 + wr * 64 + (lane >> 4) * 4;
    const int cbase = wc * 64 + (lane & 15);
    if (POOL) {
        int last = m0 + 127; if (last >= N_NODES) last = N_NODES - 1;
        const int gfirst = batch[m0 < N_NODES ? m0 : N_NODES - 1];
        const bool uniform = (batch[last] == gfirst);
        if (uniform) {
            // whole block in one graph (~92% of blocks): LDS max-reduce.
            __syncthreads();  // all waves done with GEMM LDS
            unsigned* sl = (unsigned*)Al;
            if (tid < 256) sl[tid] = ENC_NEG_INF;
            __syncthreads();
#pragma unroll
            for (int fj = 0; fj < 4; ++fj) {
                int col = cbase + fj * 16;
                float bcol = bias[col];
                float m = -3.402823466e+38f;
                bool any = false;
#pragma unroll
                for (int fi = 0; fi < 4; ++fi) {
#pragma unroll
                    for (int r = 0; r < 4; ++r) {
                        int row = rbase + fi * 16 + r;
                        if (row >= N_NODES) continue;
                        m = fmaxf(m, acc[fi][fj][r] + bcol);
                        any = true;
                    }
                }
                if (any) atomicMax(&sl[col], enc_f32(m));
            }
            __syncthreads();
            if (tid < 256) atomicMax(&pooled[gfirst * 256 + tid], sl[tid]);
        } else {
            // boundary block: verified run-length path.
#pragma unroll
            for (int fj = 0; fj < 4; ++fj) {
                int col = cbase + fj * 16;
                float bcol = bias[col];
                int curg = -1;
                float curmax = 0.f;
#pragma unroll
                for (int fi = 0; fi < 4; ++fi) {
#pragma unroll
                    for (int r = 0; r < 4; ++r) {
                        int row = rbase + fi * 16 + r;
                        if (row >= N_NODES) continue;
                        float v = acc[fi][fj][r] + bcol;
                        int g = batch[row];
                        if (g != curg) {
                            if (curg >= 0) atomicMax(&pooled[curg * 256 + col], enc_f32(curmax));
                            curg = g;
                            curmax = v;
                        } else {
                            curmax = fmaxf(curmax, v);
                        }
                    }
                }
                if (curg >= 0) atomicMax(&pooled[curg * 256 + col], enc_f32(curmax));
            }
        }
    } else {
#pragma unroll
        for (int fi = 0; fi < 4; ++fi) {
#pragma unroll
            for (int fj = 0; fj < 4; ++fj) {
                int col = cbase + fj * 16;
                float bcol = bias[col];
#pragma unroll
                for (int r = 0; r < 4; ++r) {
                    int row = rbase + fi * 16 + r;
                    if (row >= N_NODES) continue;
                    float v = acc[fi][fj][r] + bcol;
                    if (TANH) v = fast_tanh(v);
                    out[(size_t)row * 256 + col] = f2bf(v);
                }
            }
        }
    }
}

// ================= head =================
__global__ void k_head(const unsigned* __restrict__ pooled,
                       const float* __restrict__ W1, const float* __restrict__ b1,
                       const float* __restrict__ W2, const float* __restrict__ b2,
                       float* __restrict__ out) {
    __shared__ float p[256];
    __shared__ float hm[64];
    int g = blockIdx.x;
    int t = threadIdx.x;  // 64 threads
    for (int k = t; k < 256; k += 64) {
        unsigned u = pooled[g * 256 + k];
        p[k] = (u == ENC_NEG_INF) ? 0.0f : dec_f32(u);
    }
    __syncthreads();
    float a = b1[t];
    for (int k = 0; k < 256; ++k) a += p[k] * W1[k * 64 + t];
    hm[t] = tanhf(a);
    __syncthreads();
    if (t < 3) {
        float o = b2[t];
        for (int m = 0; m < 64; ++m) o += hm[m] * W2[m * 3 + t];
        out[g * 3 + t] = o;
    }
}

extern "C" void kernel_launch(void* const* d_in, const int* in_sizes, int n_in,
                              void* d_out, int out_size, void* d_ws, size_t ws_size,
                              hipStream_t stream) {
    const float* x     = (const float*)d_in[0];
    const int*   ei    = (const int*)d_in[1];
    const int*   src   = ei;
    const int*   dst   = ei + N_EDGES;
    const int*   batch = (const int*)d_in[2];
    const float* W1l = (const float*)d_in[3];
    const float* b1l = (const float*)d_in[4];
    const float* W1r = (const float*)d_in[5];
    const float* W2l = (const float*)d_in[6];
    const float* b2l = (const float*)d_in[7];
    const float* W2r = (const float*)d_in[8];
    const float* W3l = (const float*)d_in[9];
    const float* b3l = (const float*)d_in[10];
    const float* W3r = (const float*)d_in[11];
    const float* Wlin1 = (const float*)d_in[12];
    const float* blin1 = (const float*)d_in[13];
    const float* Wlin2 = (const float*)d_in[14];
    const float* blin2 = (const float*)d_in[15];
    float* out = (float*)d_out;

    // ---- workspace layout (~159 MB) ----
    char* base = (char*)d_ws;
    size_t off = 0;
    auto alloc = [&](size_t bytes) { char* p = base + off; off += (bytes + 255) & ~(size_t)255; return (void*)p; };
    int*   counts  = (int*)alloc(N_NODES * 4);
    int*   indptr  = (int*)alloc((N_NODES + 1) * 4);
    int*   cursor  = (int*)alloc(N_NODES * 4);
    int*   excl    = (int*)alloc(N_NODES * 4);
    int*   bsums   = (int*)alloc(128 * 4);
    float* deg_inv = (float*)alloc(N_NODES * 4);
    unsigned* pooled = (unsigned*)alloc(N_GRAPHS * 256 * 4);
    int*   eidx    = (int*)alloc(N_EDGES * 4);
    unsigned short* Wt1l = (unsigned short*)alloc(256 * 128 * 2);
    unsigned short* Wt1r = (unsigned short*)alloc(256 * 128 * 2);
    unsigned short* Wt2l = (unsigned short*)alloc(256 * 256 * 2);
    unsigned short* Wt2r = (unsigned short*)alloc(256 * 256 * 2);
    unsigned short* Wt3l = (unsigned short*)alloc(256 * 256 * 2);
    unsigned short* Wt3r = (unsigned short*)alloc(256 * 256 * 2);
    unsigned short* M   = (unsigned short*)alloc((size_t)N_PAD * 256 * 2);
    unsigned short* hA  = (unsigned short*)alloc((size_t)N_PAD * 256 * 2);
    unsigned short* hxB = (unsigned short*)alloc((size_t)N_PAD * 256 * 2);  // hx (conv1), then hB
    unsigned short* hx = hxB;
    unsigned short* hB = hxB;

    const int NB_SCAN = (N_NODES + 1023) / 1024;
    const int NB_AGG = (N_NODES + 63) / 64;  // 1563

    // ---- CSR build ----
    k_init_counts<<<(N_NODES + 255) / 256, 256, 0, stream>>>(counts);
    k_count<<<(N_EDGES + 255) / 256, 256, 0, stream>>>(dst, counts);
    k_scan_block<<<NB_SCAN, 1024, 0, stream>>>(counts, excl, bsums);
    k_scan_top<<<1, 128, 0, stream>>>(bsums, NB_SCAN);
    k_scan_finish<<<(N_NODES + 255) / 256, 256, 0, stream>>>(excl, bsums, counts, indptr, cursor, deg_inv, pooled);
    k_fill<<<(N_EDGES + 255) / 256, 256, 0, stream>>>(src, dst, cursor, eidx);

    // ---- conversions ----
    k_x2bf<<<2048, 256, 0, stream>>>(x, hx);
    k_wt_all<<<1280, 256, 0, stream>>>(W1l, W1r, W2l, W2r, W3l, W3r,
                                       Wt1l, Wt1r, Wt2l, Wt2r, Wt3l, Wt3r);

    dim3 ggrid(782);  // 782*128 = 100096 rows; full 256 cols per block

    // ---- conv1: x -> hA (gather + xform both on bf16 hx) ----
    k_agg<128><<<NB_AGG, 256, 0, stream>>>(hx, indptr, eidx, deg_inv, M);
    k_xform<128, true, false><<<ggrid, 512, 0, stream>>>(M, hx, Wt1l, Wt1r, b1l, hA, nullptr, nullptr);

    // ---- conv2: hA -> hB (hx dead from here) ----
    k_agg<256><<<NB_AGG, 256, 0, stream>>>(hA, indptr, eidx, deg_inv, M);
    k_xform<256, true, false><<<ggrid, 512, 0, stream>>>(M, hA, Wt2l, Wt2r, b2l, hB, nullptr, nullptr);

    // ---- conv3: hB -> pooled (fused segment-max) ----
    k_agg<256><<<NB_AGG, 256, 0, stream>>>(hB, indptr, eidx, deg_inv, M);
    k_xform<256, false, true><<<ggrid, 512, 0, stream>>>(M, hB, Wt3l, Wt3r, b3l, nullptr, batch, pooled);

    // ---- head ----
    k_head<<<N_GRAPHS, 64, 0, stream>>>(pooled, Wlin1, blin1, Wlin2, blin2, out);
}

// Round 13
// 437.654 us; speedup vs baseline: 1.3011x; 1.0399x over previous
//
#include <hip/hip_runtime.h>

#define N_NODES 100000
#define N_PAD   100224   // padded row count for A-side buffers, 128-aligned
#define N_EDGES 800000
#define N_GRAPHS 64
#define D_IN 128
#define D_H 256

typedef __attribute__((ext_vector_type(8))) short bf16x8;
typedef __attribute__((ext_vector_type(8))) unsigned short u16x8;
typedef __attribute__((ext_vector_type(4))) float f32x4;

// ---------- bf16 helpers ----------
__device__ inline float bf2f(unsigned short u) {
    union { unsigned u32; float f; } x;
    x.u32 = ((unsigned)u) << 16;
    return x.f;
}
__device__ inline unsigned short f2bf(float f) {
    unsigned u = __float_as_uint(f);
    if ((u & 0x7fffffffu) > 0x7f800000u) return (unsigned short)0x7fc0;  // NaN
    unsigned r = ((u >> 16) & 1u) + 0x7fffu;
    return (unsigned short)((u + r) >> 16);
}

// fast tanh: 1 - 2/(1+2^(2x*log2e)); v_exp_f32 + v_rcp_f32, ~5 VALU ops.
__device__ inline float fast_tanh(float x) {
    float e = __builtin_exp2f(x * 2.8853900817779268f);
    return 1.0f - 2.0f * __builtin_amdgcn_rcpf(1.0f + e);
}

// ---------- order-preserving f32 <-> u32 for atomicMax ----------
__device__ inline unsigned enc_f32(float f) {
    unsigned u = __float_as_uint(f);
    return (u & 0x80000000u) ? ~u : (u | 0x80000000u);
}
__device__ inline float dec_f32(unsigned u) {
    unsigned v = (u & 0x80000000u) ? (u & 0x7FFFFFFFu) : ~u;
    return __uint_as_float(v);
}
#define ENC_NEG_INF 0x007FFFFFu

#define GLOAD_LDS16(g, l)                                                     \
    __builtin_amdgcn_global_load_lds(                                         \
        (const __attribute__((address_space(1))) unsigned int*)(g),           \
        (__attribute__((address_space(3))) unsigned int*)(l), 16, 0, 0)

// ================= CSR build =================
__global__ void k_init_counts(int* __restrict__ counts) {
    int i = blockIdx.x * blockDim.x + threadIdx.x;
    if (i < N_NODES) counts[i] = 0;
}

__global__ void k_count(const int* __restrict__ dst, int* __restrict__ counts) {
    int e = blockIdx.x * blockDim.x + threadIdx.x;
    if (e < N_EDGES) atomicAdd(&counts[dst[e]], 1);
}

__global__ void k_scan_block(const int* __restrict__ counts, int* __restrict__ excl,
                             int* __restrict__ bsums) {
    __shared__ int sh[1024];
    int tid = threadIdx.x;
    int i = blockIdx.x * 1024 + tid;
    int v = (i < N_NODES) ? counts[i] : 0;
    sh[tid] = v;
    __syncthreads();
    for (int off = 1; off < 1024; off <<= 1) {
        int t = (tid >= off) ? sh[tid - off] : 0;
        __syncthreads();
        sh[tid] += t;
        __syncthreads();
    }
    if (i < N_NODES) excl[i] = sh[tid] - v;
    if (tid == 1023) bsums[blockIdx.x] = sh[1023];
}

__global__ void k_scan_top(int* __restrict__ bsums, int nb) {
    __shared__ int sh[128];
    int tid = threadIdx.x;
    int v = (tid < nb) ? bsums[tid] : 0;
    sh[tid] = v;
    __syncthreads();
    for (int off = 1; off < 128; off <<= 1) {
        int t = (tid >= off) ? sh[tid - off] : 0;
        __syncthreads();
        sh[tid] += t;
        __syncthreads();
    }
    if (tid < nb) bsums[tid] = sh[tid] - v;
}

__global__ void k_scan_finish(const int* __restrict__ excl, const int* __restrict__ bsums,
                              const int* __restrict__ counts, int* __restrict__ indptr,
                              int* __restrict__ cursor, float* __restrict__ deg_inv,
                              unsigned* __restrict__ pooled) {
    int i = blockIdx.x * blockDim.x + threadIdx.x;
    if (i < N_GRAPHS * 256) pooled[i] = ENC_NEG_INF;  // fold pool_init here
    if (i < N_NODES) {
        int p = excl[i] + bsums[i >> 10];
        indptr[i] = p;
        cursor[i] = p;
        deg_inv[i] = 1.0f / fmaxf((float)counts[i], 1.0f);
        if (i == 0) indptr[N_NODES] = N_EDGES;
    }
}

__global__ void k_fill(const int* __restrict__ src, const int* __restrict__ dst,
                       int* __restrict__ cursor, int* __restrict__ eidx) {
    int e = blockIdx.x * blockDim.x + threadIdx.x;
    if (e < N_EDGES) {
        int pos = atomicAdd(&cursor[dst[e]], 1);
        eidx[pos] = src[e];
    }
}

// ================= conversions =================
__global__ void k_x2bf(const float* __restrict__ x, unsigned short* __restrict__ hx) {
    const int total = N_NODES * D_IN / 4;
    for (int i = blockIdx.x * blockDim.x + threadIdx.x; i < total;
         i += gridDim.x * blockDim.x) {
        float4 v = reinterpret_cast<const float4*>(x)[i];
        ushort4 o;
        o.x = f2bf(v.x); o.y = f2bf(v.y); o.z = f2bf(v.z); o.w = f2bf(v.w);
        reinterpret_cast<ushort4*>(hx)[i] = o;
    }
}

// All six W [K][256] f32 -> Wt [256][K] bf16 in one launch.
__global__ void k_wt_all(const float* __restrict__ W1l, const float* __restrict__ W1r,
                         const float* __restrict__ W2l, const float* __restrict__ W2r,
                         const float* __restrict__ W3l, const float* __restrict__ W3r,
                         unsigned short* __restrict__ T1l, unsigned short* __restrict__ T1r,
                         unsigned short* __restrict__ T2l, unsigned short* __restrict__ T2r,
                         unsigned short* __restrict__ T3l, unsigned short* __restrict__ T3r) {
    const int S1 = 128 * 256, S2 = 256 * 256;
    const int total = 2 * S1 + 4 * S2;
    for (int idx = blockIdx.x * blockDim.x + threadIdx.x; idx < total;
         idx += gridDim.x * blockDim.x) {
        const float* W; unsigned short* T; int i, K;
        if (idx < S1)           { W = W1l; T = T1l; i = idx;            K = 128; }
        else if (idx < 2 * S1)  { W = W1r; T = T1r; i = idx - S1;       K = 128; }
        else if (idx < 2*S1+S2) { W = W2l; T = T2l; i = idx - 2*S1;     K = 256; }
        else if (idx < 2*S1+2*S2) { W = W2r; T = T2r; i = idx-2*S1-S2;  K = 256; }
        else if (idx < 2*S1+3*S2) { W = W3l; T = T3l; i = idx-2*S1-2*S2; K = 256; }
        else                    { W = W3r; T = T3r; i = idx-2*S1-3*S2;  K = 256; }
        int k = i >> 8, n = i & 255;
        T[n * K + k] = f2bf(W[(size_t)k * 256 + n]);
    }
}

// ================= aggregation: mean over CSR neighbors =================
// NB=32 nodes/block -> 3125 blocks (~8 resident blocks/CU = full wave slots),
// doubling outstanding gather misses vs NB=64 (grid-limited at 49% occupancy).
// Indices LDS-staged (r11-verified); explicit u32 lo/hi bf16 unpack (2 VALU/elem).
template <int D>
__global__ __launch_bounds__(256)
void k_agg(const unsigned short* __restrict__ hin, const int* __restrict__ indptr,
           const int* __restrict__ eidx, const float* __restrict__ deg_inv,
           unsigned short* __restrict__ mean) {
    constexpr int NB = 32;
    constexpr int ECAP = 640;
    constexpr int CA = (D == 128) ? 8 : 16;   // f32 accum elems per lane
    __shared__ int sptr[NB + 1];
    __shared__ int sedge[ECAP];

    const int n0 = blockIdx.x * NB;
    const int tid = threadIdx.x;

    if (tid <= NB) {
        int n = n0 + tid;
        sptr[tid] = indptr[n < N_NODES ? n : N_NODES];
    }
    __syncthreads();
    const int ebeg = sptr[0];
    const int ecnt = sptr[NB] - ebeg;
    const int estaged = ecnt < ECAP ? ecnt : ECAP;
    for (int i = tid; i < estaged; i += 256) sedge[i] = eidx[ebeg + i];
    __syncthreads();

    const int wv = tid >> 6;     // 0..3: wave handles nodes n0+wv*8 .. +7
    const int lane = tid & 63;
    const int g = lane >> 4;     // edge slot 0..3
    const int l16 = lane & 15;   // 16 lanes cover one row

    for (int i = 0; i < 8; ++i) {
        int ln = wv * 8 + i;
        int node = n0 + ln;
        if (node >= N_NODES) break;
        int b = sptr[ln] - ebeg, e = sptr[ln + 1] - ebeg;
        float acc[CA] = {};
        for (int j = b + g; j < e; j += 4) {
            int s = (j < ECAP) ? sedge[j] : eidx[ebeg + j];
            const uint4* row = reinterpret_cast<const uint4*>(hin + (size_t)s * D);
            if (D == 128) {
                uint4 a = row[l16];
                const unsigned uu[4] = {a.x, a.y, a.z, a.w};
#pragma unroll
                for (int c = 0; c < 4; ++c) {
                    acc[2 * c]     += __uint_as_float(uu[c] << 16);
                    acc[2 * c + 1] += __uint_as_float(uu[c] & 0xffff0000u);
                }
            } else {
                uint4 a0 = row[l16 * 2], a1 = row[l16 * 2 + 1];
                const unsigned uu[8] = {a0.x, a0.y, a0.z, a0.w, a1.x, a1.y, a1.z, a1.w};
#pragma unroll
                for (int c = 0; c < 8; ++c) {
                    acc[2 * c]     += __uint_as_float(uu[c] << 16);
                    acc[2 * c + 1] += __uint_as_float(uu[c] & 0xffff0000u);
                }
            }
        }
#pragma unroll
        for (int c = 0; c < CA; ++c) {
            acc[c] += __shfl_xor(acc[c], 16);
            acc[c] += __shfl_xor(acc[c], 32);
        }
        if (g == 0) {
            float inv = deg_inv[node];
            unsigned short* orow = mean + (size_t)node * D;
            if (D == 128) {
                u16x8 o;
#pragma unroll
                for (int c = 0; c < 8; ++c) o[c] = f2bf(acc[c] * inv);
                reinterpret_cast<u16x8*>(orow)[l16] = o;
            } else {
                u16x8 o0, o1;
#pragma unroll
                for (int c = 0; c < 8; ++c) o0[c] = f2bf(acc[c] * inv);
#pragma unroll
                for (int c = 0; c < 8; ++c) o1[c] = f2bf(acc[8 + c] * inv);
                reinterpret_cast<u16x8*>(orow)[l16 * 2] = o0;
                reinterpret_cast<u16x8*>(orow)[l16 * 2 + 1] = o1;
            }
        }
    }
}

// ================= MFMA SAGE transform =================
// r7-verified GEMM core + r12-verified epilogue (fast_tanh; uniform-graph
// LDS pool reduce). Unchanged this round.
template <int K, bool TANH, bool POOL>
__global__ __launch_bounds__(512)
void k_xform(const unsigned short* __restrict__ A0, const unsigned short* __restrict__ A1,
             const unsigned short* __restrict__ Bt0, const unsigned short* __restrict__ Bt1,
             const float* __restrict__ bias,
             unsigned short* __restrict__ out,
             const int* __restrict__ batch, unsigned* __restrict__ pooled) {
    __shared__ unsigned short Al[128 * 32];
    __shared__ unsigned short Bl[256 * 32];

    const int tid = threadIdx.x;
    const int lane = tid & 63;
    const int wid = tid >> 6;        // 0..7
    const int wr = wid >> 2;         // wave row (0..1)
    const int wc = wid & 3;          // wave col (0..3)
    const int m0 = blockIdx.x * 128;

    const int srow = lane >> 2;                         // 0..15 within 16-row group
    const int koffs = ((lane & 3) ^ ((lane >> 3) & 3)) * 8;

    f32x4 acc[4][4] = {};

#pragma unroll
    for (int slab = 0; slab < 2; ++slab) {
        const unsigned short* As = slab ? A1 : A0;
        const unsigned short* Bs = slab ? Bt1 : Bt0;
        for (int k0 = 0; k0 < K; k0 += 32) {
            __syncthreads();  // previous compute done before overwrite
            GLOAD_LDS16(As + (size_t)(m0 + wid * 16 + srow) * K + k0 + koffs,
                        &Al[wid * 512]);
#pragma unroll
            for (int cc = 0; cc < 2; ++cc) {
                int c = wid * 2 + cc;
                GLOAD_LDS16(Bs + (size_t)(c * 16 + srow) * K + k0 + koffs,
                            &Bl[c * 512]);
            }
            asm volatile("s_waitcnt vmcnt(0)" ::: "memory");
            __syncthreads();

            bf16x8 af[4], bfr[4];
#pragma unroll
            for (int f = 0; f < 4; ++f) {
                int ra = wr * 64 + f * 16 + (lane & 15);
                int pa = ((lane >> 4) ^ ((ra >> 1) & 3)) * 8;
                af[f] = *reinterpret_cast<const bf16x8*>(&Al[ra * 32 + pa]);
                int rb = wc * 64 + f * 16 + (lane & 15);
                int pb = ((lane >> 4) ^ ((rb >> 1) & 3)) * 8;
                bfr[f] = *reinterpret_cast<const bf16x8*>(&Bl[rb * 32 + pb]);
            }
#pragma unroll
            for (int fi = 0; fi < 4; ++fi)
#pragma unroll
                for (int fj = 0; fj < 4; ++fj)
                    acc[fi][fj] = __builtin_amdgcn_mfma_f32_16x16x32_bf16(
                        af[fi], bfr[fj], acc[fi][fj], 0, 0, 0);
        }
    }

    // epilogue: D mapping per frag: row = (lane>>4)*4 + r, col = lane&15
    const int rbase = m0 + wr * 64 + (lane >> 4) * 4;
    const int cbase = wc * 64 + (lane & 15);
    if (POOL) {
        int last = m0 + 127; if (last >= N_NODES) last = N_NODES - 1;
        const int gfirst = batch[m0 < N_NODES ? m0 : N_NODES - 1];
        const bool uniform = (batch[last] == gfirst);
        if (uniform) {
            __syncthreads();  // all waves done with GEMM LDS
            unsigned* sl = (unsigned*)Al;
            if (tid < 256) sl[tid] = ENC_NEG_INF;
            __syncthreads();
#pragma unroll
            for (int fj = 0; fj < 4; ++fj) {
                int col = cbase + fj * 16;
                float bcol = bias[col];
                float m = -3.402823466e+38f;
                bool any = false;
#pragma unroll
                for (int fi = 0; fi < 4; ++fi) {
#pragma unroll
                    for (int r = 0; r < 4; ++r) {
                        int row = rbase + fi * 16 + r;
                        if (row >= N_NODES) continue;
                        m = fmaxf(m, acc[fi][fj][r] + bcol);
                        any = true;
                    }
                }
                if (any) atomicMax(&sl[col], enc_f32(m));
            }
            __syncthreads();
            if (tid < 256) atomicMax(&pooled[gfirst * 256 + tid], sl[tid]);
        } else {
#pragma unroll
            for (int fj = 0; fj < 4; ++fj) {
                int col = cbase + fj * 16;
                float bcol = bias[col];
                int curg = -1;
                float curmax = 0.f;
#pragma unroll
                for (int fi = 0; fi < 4; ++fi) {
#pragma unroll
                    for (int r = 0; r < 4; ++r) {
                        int row = rbase + fi * 16 + r;
                        if (row >= N_NODES) continue;
                        float v = acc[fi][fj][r] + bcol;
                        int g = batch[row];
                        if (g != curg) {
                            if (curg >= 0) atomicMax(&pooled[curg * 256 + col], enc_f32(curmax));
                            curg = g;
                            curmax = v;
                        } else {
                            curmax = fmaxf(curmax, v);
                        }
                    }
                }
                if (curg >= 0) atomicMax(&pooled[curg * 256 + col], enc_f32(curmax));
            }
        }
    } else {
#pragma unroll
        for (int fi = 0; fi < 4; ++fi) {
#pragma unroll
            for (int fj = 0; fj < 4; ++fj) {
                int col = cbase + fj * 16;
                float bcol = bias[col];
#pragma unroll
                for (int r = 0; r < 4; ++r) {
                    int row = rbase + fi * 16 + r;
                    if (row >= N_NODES) continue;
                    float v = acc[fi][fj][r] + bcol;
                    if (TANH) v = fast_tanh(v);
                    out[(size_t)row * 256 + col] = f2bf(v);
                }
            }
        }
    }
}

// ================= head =================
__global__ void k_head(const unsigned* __restrict__ pooled,
                       const float* __restrict__ W1, const float* __restrict__ b1,
                       const float* __restrict__ W2, const float* __restrict__ b2,
                       float* __restrict__ out) {
    __shared__ float p[256];
    __shared__ float hm[64];
    int g = blockIdx.x;
    int t = threadIdx.x;  // 64 threads
    for (int k = t; k < 256; k += 64) {
        unsigned u = pooled[g * 256 + k];
        p[k] = (u == ENC_NEG_INF) ? 0.0f : dec_f32(u);
    }
    __syncthreads();
    float a = b1[t];
    for (int k = 0; k < 256; ++k) a += p[k] * W1[k * 64 + t];
    hm[t] = tanhf(a);
    __syncthreads();
    if (t < 3) {
        float o = b2[t];
        for (int m = 0; m < 64; ++m) o += hm[m] * W2[m * 3 + t];
        out[g * 3 + t] = o;
    }
}

extern "C" void kernel_launch(void* const* d_in, const int* in_sizes, int n_in,
                              void* d_out, int out_size, void* d_ws, size_t ws_size,
                              hipStream_t stream) {
    const float* x     = (const float*)d_in[0];
    const int*   ei    = (const int*)d_in[1];
    const int*   src   = ei;
    const int*   dst   = ei + N_EDGES;
    const int*   batch = (const int*)d_in[2];
    const float* W1l = (const float*)d_in[3];
    const float* b1l = (const float*)d_in[4];
    const float* W1r = (const float*)d_in[5];
    const float* W2l = (const float*)d_in[6];
    const float* b2l = (const float*)d_in[7];
    const float* W2r = (const float*)d_in[8];
    const float* W3l = (const float*)d_in[9];
    const float* b3l = (const float*)d_in[10];
    const float* W3r = (const float*)d_in[11];
    const float* Wlin1 = (const float*)d_in[12];
    const float* blin1 = (const float*)d_in[13];
    const float* Wlin2 = (const float*)d_in[14];
    const float* blin2 = (const float*)d_in[15];
    float* out = (float*)d_out;

    // ---- workspace layout (~159 MB) ----
    char* base = (char*)d_ws;
    size_t off = 0;
    auto alloc = [&](size_t bytes) { char* p = base + off; off += (bytes + 255) & ~(size_t)255; return (void*)p; };
    int*   counts  = (int*)alloc(N_NODES * 4);
    int*   indptr  = (int*)alloc((N_NODES + 1) * 4);
    int*   cursor  = (int*)alloc(N_NODES * 4);
    int*   excl    = (int*)alloc(N_NODES * 4);
    int*   bsums   = (int*)alloc(128 * 4);
    float* deg_inv = (float*)alloc(N_NODES * 4);
    unsigned* pooled = (unsigned*)alloc(N_GRAPHS * 256 * 4);
    int*   eidx    = (int*)alloc(N_EDGES * 4);
    unsigned short* Wt1l = (unsigned short*)alloc(256 * 128 * 2);
    unsigned short* Wt1r = (unsigned short*)alloc(256 * 128 * 2);
    unsigned short* Wt2l = (unsigned short*)alloc(256 * 256 * 2);
    unsigned short* Wt2r = (unsigned short*)alloc(256 * 256 * 2);
    unsigned short* Wt3l = (unsigned short*)alloc(256 * 256 * 2);
    unsigned short* Wt3r = (unsigned short*)alloc(256 * 256 * 2);
    unsigned short* M   = (unsigned short*)alloc((size_t)N_PAD * 256 * 2);
    unsigned short* hA  = (unsigned short*)alloc((size_t)N_PAD * 256 * 2);
    unsigned short* hxB = (unsigned short*)alloc((size_t)N_PAD * 256 * 2);  // hx (conv1), then hB
    unsigned short* hx = hxB;
    unsigned short* hB = hxB;

    const int NB_SCAN = (N_NODES + 1023) / 1024;
    const int NB_AGG = (N_NODES + 31) / 32;  // 3125

    // ---- CSR build ----
    k_init_counts<<<(N_NODES + 255) / 256, 256, 0, stream>>>(counts);
    k_count<<<(N_EDGES + 255) / 256, 256, 0, stream>>>(dst, counts);
    k_scan_block<<<NB_SCAN, 1024, 0, stream>>>(counts, excl, bsums);
    k_scan_top<<<1, 128, 0, stream>>>(bsums, NB_SCAN);
    k_scan_finish<<<(N_NODES + 255) / 256, 256, 0, stream>>>(excl, bsums, counts, indptr, cursor, deg_inv, pooled);
    k_fill<<<(N_EDGES + 255) / 256, 256, 0, stream>>>(src, dst, cursor, eidx);

    // ---- conversions ----
    k_x2bf<<<2048, 256, 0, stream>>>(x, hx);
    k_wt_all<<<1280, 256, 0, stream>>>(W1l, W1r, W2l, W2r, W3l, W3r,
                                       Wt1l, Wt1r, Wt2l, Wt2r, Wt3l, Wt3r);

    dim3 ggrid(782);  // 782*128 = 100096 rows; full 256 cols per block

    // ---- conv1: x -> hA (gather + xform both on bf16 hx) ----
    k_agg<128><<<NB_AGG, 256, 0, stream>>>(hx, indptr, eidx, deg_inv, M);
    k_xform<128, true, false><<<ggrid, 512, 0, stream>>>(M, hx, Wt1l, Wt1r, b1l, hA, nullptr, nullptr);

    // ---- conv2: hA -> hB (hx dead from here) ----
    k_agg<256><<<NB_AGG, 256, 0, stream>>>(hA, indptr, eidx, deg_inv, M);
    k_xform<256, true, false><<<ggrid, 512, 0, stream>>>(M, hA, Wt2l, Wt2r, b2l, hB, nullptr, nullptr);

    // ---- conv3: hB -> pooled (fused segment-max) ----
    k_agg<256><<<NB_AGG, 256, 0, stream>>>(hB, indptr, eidx, deg_inv, M);
    k_xform<256, false, true><<<ggrid, 512, 0, stream>>>(M, hB, Wt3l, Wt3r, b3l, nullptr, batch, pooled);

    // ---- head ----
    k_head<<<N_GRAPHS, 64, 0, stream>>>(pooled, Wlin1, blin1, Wlin2, blin2, out);
}